// Round 5
// baseline (85.618 us; speedup 1.0000x reference)
//
#include <hip/hip_runtime.h>
#include <math.h>

// KDE via GEMM trick, v17 = v15 cadence + 32x32x16 MFMA + pre-exp'd col norms.
//   density[i] = (1/M) * sum_j exp2(2c*dot + u_i) * edv_j
//   u_i = -c|x|^2 - log2M (MFMA C-operand init), edv_j = exp2(-c|d|^2) (prep)
//
// CROSS-ROUND MODEL (r9-v16): all scheduling/volume restructures are +-1us
// (v14 2x occupancy: +0.75; v13 VMEM/4: -1; v16 barriers/2: +1..2; r12
// direct-stream: par). All wins are arithmetic-floor/dispatch cuts (v15:
// -4.8). v17 cuts the largest pipe floor: MFMA 16x16x32 @2075TF = 8.3us
// device -> 32x32x16 @2382TF = 6.9us, and halves MFMA issue count. Phase
// cadence identical to v15 (16 phases, 8KB staged/phase, stage-after-
// barrier, 2x8KB dbuf, 4 blocks/CU pinned).
// [r4: bench infra failure ("container failed twice"), no kernel verdict;
//  kernel re-audited (mappings, bounds, loops) and resubmitted unchanged.]
//
// Fragment mappings:
//   16x16 (prep norms path unchanged); 32x32x16_f16:
//   A: row=lane&31, k=(lane>>5)*8+j   (standard CDNA pattern, session-
//   B: col=lane&31, k=(lane>>5)*8+j    verified at 16x16, scaled)
//   C/D: col=lane&31, row=(reg&3)+8*(reg>>2)+4*(lane>>5)  [m74/m101]
// global_load_lds: LDS dest = wave-uniform base + lane*16 (verified m104);
// df's fragment-major layout matches exactly.
// fp16 single-pass accuracy verified r4-v16: absmax ~2.8e-17 vs 2.4e-16.

#define D_DIM 128
#define TPG   16   // 32-col tiles per col-group (512 cols); 16 phases

typedef _Float16 f16x8 __attribute__((ext_vector_type(8)));
typedef _Float16 f16x4 __attribute__((ext_vector_type(4)));
typedef __attribute__((ext_vector_type(4))) float f32x4;
typedef __attribute__((ext_vector_type(16))) float f32x16;

#define C2F   ((float)(0.5 / 2.50662827463100050242 * 1.44269504088896340736))
#define TWOC2 (2.0f * C2F)

// ---- prep: fp32 -> fp16 32-wide fragment-major + norms ------------------
// Layout (both sides): tile t (32 rows), k-chunk kc (16 dims):
//   elem (row, k): halves[ (t*8+kc)*512 + (half*32 + (row&31))*8 + (k&7) ]
//   with half = (k>>3)&1; k = kc*16 + half*8 + j.
__global__ __launch_bounds__(256)
void prep_kernel(const float* __restrict__ x, const float* __restrict__ data,
                 _Float16* __restrict__ xf, _Float16* __restrict__ df,
                 float* __restrict__ xn_u, float* __restrict__ dn_e,
                 float* __restrict__ out, int xThreads, float negLogM) {
    const int gid = blockIdx.x * 256 + threadIdx.x;
    const int which = (gid >= xThreads);
    const int id = which ? (gid - xThreads) : gid;
    const int row = id >> 5, seg = id & 31;     // seg covers dims seg*4..+3
    const float* src = which ? data : x;
    _Float16* dst = which ? df : xf;

    const float4 v = *(const float4*)&src[(size_t)row * D_DIM + seg * 4];

    const int t = row >> 5, rr = row & 31;
    const int kc = seg >> 2, half = (seg >> 1) & 1, j0 = (seg & 1) * 4;
    const float sc = which ? 1.0f : TWOC2;   // scale x-side only
    f16x4 h;
    h[0] = (_Float16)(v.x * sc); h[1] = (_Float16)(v.y * sc);
    h[2] = (_Float16)(v.z * sc); h[3] = (_Float16)(v.w * sc);
    *(f16x4*)&dst[(size_t)(t * 8 + kc) * 512 + (half * 32 + rr) * 8 + j0] = h;

    // norms from UNSCALED values
    float nrm = fmaf(v.x, v.x, fmaf(v.y, v.y, fmaf(v.z, v.z, v.w * v.w)));
#pragma unroll
    for (int off = 1; off < 32; off <<= 1) nrm += __shfl_xor(nrm, off, 64);
    if (seg == 0) {
        if (which) dn_e[row] = __builtin_amdgcn_exp2f(-C2F * nrm);  // pre-exp'd
        else {
            xn_u[row] = fmaf(-C2F, nrm, negLogM);
            out[row]  = 0.0f;                 // fused d_out zeroing
        }
    }
}

// ---- main: 4 waves x 32 rows, LDS-shared B, one 32-col tile per barrier --
__global__ __launch_bounds__(256)
__attribute__((amdgpu_waves_per_eu(4, 4)))
void kde_f16v17(const _Float16* __restrict__ xf, const _Float16* __restrict__ df,
                const float* __restrict__ xn_u, const float* __restrict__ dn_e,
                float* __restrict__ out, int colGroups) {
    // Double buffer: each holds one 32-col B tile (8 KB = 4096 halves).
    // Chunk kc (0..7) at sh[buf][kc*512 .. +512) halves.
    __shared__ _Float16 sh[2][4096];

    const int tid  = threadIdx.x;
    const int lane = tid & 63;
    const int w    = tid >> 6;
    const int c32  = lane & 31;      // this lane's column within a tile
    const int hl   = lane >> 5;      // lane half

    const int bid = blockIdx.x;
    const int cg  = bid % colGroups;
    const int rb  = bid / colGroups;
    const int rowBase = rb * 128 + w * 32;   // this wave's 32 rows
    const int ct0     = cg * TPG;            // first 32-col tile index

    // A fragments: 8 coalesced 16B loads, once (one 32-row tile, K=128).
    f16x8 af[8];
    {
        const int tA = rb * 4 + w;
#pragma unroll
        for (int kc = 0; kc < 8; ++kc)
            af[kc] = *(const f16x8*)&xf[(size_t)(tA * 8 + kc) * 512 + lane * 8];
    }

    // Row terms as MFMA C-init: uC[r] = xn_u[rowBase + (r&3)+8*(r>>2)+4*hl].
    f32x16 uC;
#pragma unroll
    for (int g = 0; g < 4; ++g) {
        const f32x4 ug = *(const f32x4*)&xn_u[rowBase + 8 * g + 4 * hl];
        uC[g * 4 + 0] = ug[0]; uC[g * 4 + 1] = ug[1];
        uC[g * 4 + 2] = ug[2]; uC[g * 4 + 3] = ug[3];
    }

    f32x16 srow;
#pragma unroll
    for (int r = 0; r < 16; ++r) srow[r] = 0.0f;

    const _Float16* dbase = &df[(size_t)ct0 * 4096];    // 4096 halves/tile
    const float*    nbase = &dn_e[ct0 * 32 + c32];      // pre-exp'd, per-col

    // Stage tile p into buffer buf: 8 chunks of 1 KB, 2 per wave.
    // Wave-uniform LDS base + lane*16 (HW scatter) matches df layout.
    auto stageTile = [&](int p, int buf) {
#pragma unroll
        for (int i = 0; i < 2; ++i) {
            const int c = w * 2 + i;           // 0..7 = kc
            const _Float16* g = &dbase[(size_t)p * 4096 + (size_t)c * 512 + (size_t)lane * 8];
            __builtin_amdgcn_global_load_lds(
                (const __attribute__((address_space(1))) void*)g,
                (__attribute__((address_space(3))) void*)&sh[buf][c * 512], 16, 0, 0);
        }
    };

// Compute one 32-col tile from LDS. acc starts at uC via the MFMA C input;
// EDV is the pre-exp'd per-column factor (prefetched plain load).
#define TILE32(BUF, EDV)                                                          \
    {                                                                             \
        f16x8 b0 = *(const f16x8*)&sh[BUF][0 * 512 + lane * 8];                   \
        f16x8 b1 = *(const f16x8*)&sh[BUF][1 * 512 + lane * 8];                   \
        f16x8 b2 = *(const f16x8*)&sh[BUF][2 * 512 + lane * 8];                   \
        f16x8 b3 = *(const f16x8*)&sh[BUF][3 * 512 + lane * 8];                   \
        f16x8 b4 = *(const f16x8*)&sh[BUF][4 * 512 + lane * 8];                   \
        f16x8 b5 = *(const f16x8*)&sh[BUF][5 * 512 + lane * 8];                   \
        f16x8 b6 = *(const f16x8*)&sh[BUF][6 * 512 + lane * 8];                   \
        f16x8 b7 = *(const f16x8*)&sh[BUF][7 * 512 + lane * 8];                   \
        f32x16 acc = __builtin_amdgcn_mfma_f32_32x32x16_f16(af[0], b0, uC, 0, 0, 0); \
        acc = __builtin_amdgcn_mfma_f32_32x32x16_f16(af[1], b1, acc, 0, 0, 0);    \
        acc = __builtin_amdgcn_mfma_f32_32x32x16_f16(af[2], b2, acc, 0, 0, 0);    \
        acc = __builtin_amdgcn_mfma_f32_32x32x16_f16(af[3], b3, acc, 0, 0, 0);    \
        acc = __builtin_amdgcn_mfma_f32_32x32x16_f16(af[4], b4, acc, 0, 0, 0);    \
        acc = __builtin_amdgcn_mfma_f32_32x32x16_f16(af[5], b5, acc, 0, 0, 0);    \
        acc = __builtin_amdgcn_mfma_f32_32x32x16_f16(af[6], b6, acc, 0, 0, 0);    \
        acc = __builtin_amdgcn_mfma_f32_32x32x16_f16(af[7], b7, acc, 0, 0, 0);    \
        _Pragma("unroll")                                                         \
        for (int r = 0; r < 16; ++r)                                              \
            srow[r] = fmaf(__builtin_amdgcn_exp2f(acc[r]), (EDV), srow[r]);       \
    }

    stageTile(0, 0);
    float e = nbase[0];   // tile-0 column factor

#pragma unroll 1
    for (int p = 0; p < TPG; ++p) {
        const int buf = p & 1;
        __syncthreads();                    // drains stage(p) (issued a full
                                            // compute phase ago) + frees buf^1
        float eNext = e;
        if (p + 1 < TPG) {
            stageTile(p + 1, buf ^ 1);      // in flight across this compute
            eNext = nbase[(p + 1) * 32];    // edv prefetch: one phase ahead
        }
        TILE32(buf, e);
        e = eNext;
    }

#undef TILE32

    // Reduce each acc row over the 32 col-lanes and accumulate to out.
#pragma unroll
    for (int rg = 0; rg < 16; ++rg) {
        float s = srow[rg];
        s += __shfl_xor(s, 1, 64);
        s += __shfl_xor(s, 2, 64);
        s += __shfl_xor(s, 4, 64);
        s += __shfl_xor(s, 8, 64);
        s += __shfl_xor(s, 16, 64);
        if (c32 == 0)
            atomicAdd(&out[rowBase + (rg & 3) + 8 * (rg >> 2) + 4 * hl], s);
    }
}

// ---------------- fallback: round-1 VALU kernel (any size, no ws) ---------
#define BN 128
#define BM 128
#define KT 32
#define LDSS 132

__global__ __launch_bounds__(256, 4)
void kde_valu(const float* __restrict__ x, const float* __restrict__ data,
              float* __restrict__ out, int N, int M) {
    __shared__ float xs[KT][LDSS];
    __shared__ float dsh[KT][LDSS];
    __shared__ float xn_s[BN];
    __shared__ float dn_s[BM];
    const int tid = threadIdx.x;
    const int ty = tid >> 4, tx = tid & 15;
    const int rowBase = blockIdx.y * BN, colBase = blockIdx.x * BM;
    float acc[8][8];
#pragma unroll
    for (int i = 0; i < 8; ++i)
#pragma unroll
        for (int j = 0; j < 8; ++j) acc[i][j] = 0.0f;
    float normAcc = 0.0f;
    for (int kc = 0; kc < D_DIM; kc += KT) {
        __syncthreads();
#pragma unroll
        for (int i = 0; i < 4; ++i) {
            const int idx = tid + i * 256;
            const int row = idx >> 3, kq = idx & 7;
            const float4 v = *(const float4*)&x[(size_t)(rowBase + row) * D_DIM + kc + kq * 4];
            xs[kq * 4 + 0][row] = v.x; xs[kq * 4 + 1][row] = v.y;
            xs[kq * 4 + 2][row] = v.z; xs[kq * 4 + 3][row] = v.w;
            const float4 wv = *(const float4*)&data[(size_t)(colBase + row) * D_DIM + kc + kq * 4];
            dsh[kq * 4 + 0][row] = wv.x; dsh[kq * 4 + 1][row] = wv.y;
            dsh[kq * 4 + 2][row] = wv.z; dsh[kq * 4 + 3][row] = wv.w;
        }
        __syncthreads();
        {
            const float* col = (tid < 128) ? &xs[0][tid] : &dsh[0][tid - 128];
#pragma unroll
            for (int k = 0; k < KT; ++k) { const float v = col[k * LDSS]; normAcc = fmaf(v, v, normAcc); }
        }
#pragma unroll
        for (int k = 0; k < KT; ++k) {
            float a[8], b[8];
            *(float4*)&a[0] = *(const float4*)&xs[k][ty * 8];
            *(float4*)&a[4] = *(const float4*)&xs[k][ty * 8 + 4];
            *(float4*)&b[0] = *(const float4*)&dsh[k][tx * 4];
            *(float4*)&b[4] = *(const float4*)&dsh[k][64 + tx * 4];
#pragma unroll
            for (int i = 0; i < 8; ++i)
#pragma unroll
                for (int j = 0; j < 8; ++j) acc[i][j] = fmaf(a[i], b[j], acc[i][j]);
        }
    }
    if (tid < 128) xn_s[tid] = normAcc; else dn_s[tid - 128] = normAcc;
    __syncthreads();
    const float C2 = C2F;
    const float negLogM = -log2f((float)M);
#pragma unroll
    for (int i = 0; i < 8; ++i) {
        const int row = ty * 8 + i;
        const float xnr = xn_s[row];
        float s = 0.0f;
#pragma unroll
        for (int j = 0; j < 8; ++j) {
            const int col = (j < 4) ? (tx * 4 + j) : (64 + tx * 4 + (j - 4));
            const float sq = xnr + dn_s[col] - 2.0f * acc[i][j];
            s += exp2f(fmaf(-C2, sq, negLogM));
        }
#pragma unroll
        for (int off = 1; off < 16; off <<= 1) s += __shfl_xor(s, off, 64);
        if (tx == 0) atomicAdd(&out[rowBase + row], s);
    }
}

extern "C" void kernel_launch(void* const* d_in, const int* in_sizes, int n_in,
                              void* d_out, int out_size, void* d_ws, size_t ws_size,
                              hipStream_t stream) {
    const float* x    = (const float*)d_in[0];
    const float* data = (const float*)d_in[1];
    float* out = (float*)d_out;
    const int N = in_sizes[0] / D_DIM;
    const int M = in_sizes[1] / D_DIM;

    const size_t need = (size_t)(N + M) * D_DIM * 2 + (size_t)(N + M) * 4;
    if (ws_size < need || (N & 127) || (M & 511)) {
        hipMemsetAsync(d_out, 0, (size_t)out_size * sizeof(float), stream);
        dim3 grid(M / BM, N / BN);
        kde_valu<<<grid, 256, 0, stream>>>(x, data, out, N, M);
        return;
    }

    _Float16* xf = (_Float16*)d_ws;
    _Float16* df = xf + (size_t)N * D_DIM;
    float* xn_u = (float*)(df + (size_t)M * D_DIM);
    float* dn_e = xn_u + N;

    const float negLogM = -log2f((float)M);
    const int xThreads = N * 32;
    const int totThreads = (N + M) * 32;
    prep_kernel<<<totThreads / 256, 256, 0, stream>>>(x, data, xf, df, xn_u, dn_e,
                                                      out, xThreads, negLogM);

    const int colGroups = M / 512;           // 512 cols/group, 16 tile-phases
    const int rowBlocks = N / 128;
    kde_f16v17<<<rowBlocks * colGroups, 256, 0, stream>>>(xf, df, xn_u, dn_e, out,
                                                          colGroups);
}

// Round 6
// 81.507 us; speedup vs baseline: 1.0504x; 1.0504x over previous
//
#include <hip/hip_runtime.h>
#include <math.h>

// KDE via GEMM trick, v18 = v15 (measured best, 80.99us) + pre-exp'd col
// norms ONLY (the clean half of v16).
//   density[i] = (1/M) * sum_j exp2(2c*dot + u_i) * edv_j
//   u_i = -c|x|^2 - log2M (MFMA C-operand init), edv_j = exp2(-c|d|^2) (prep)
//
// CROSS-ROUND MODEL (r9-v17): main is LATENCY-PACED by the per-phase
// serial chain (barrier -> ds_read -> MFMA chains -> exp2 tail), not
// pipe-bound. Evidence: all volume/occupancy/barrier restructures +-1us
// (v13 VMEM/4: -1; v14 2x waves: +0.75; v16 barriers/2: +2); v17's
// 32x32x16 single 8-deep dependent chain: +4.6us (ILP per phase is what
// matters, NOT per-MFMA cost). Wins only from arithmetic-floor/dispatch
// cuts on the tail (v15: -4.8). v18 takes the last such cut: the tail's
// exp2(dv) trans op (gates 8 fmafs, 64x redundant per column) becomes a
// prefetched plain load. Predicted ~80.0. If >=81: structural floor,
// ROOFLINE next.
//
// Fragment mappings (verified end-to-end rounds 2-16):
//   A: lane holds A[m=lane&15][k=(lane>>4)*8+j]
//   B: lane holds B^T row-major: col=lane&15, k=(lane>>4)*8+j
//   C/D: col=lane&15, row=(lane>>4)*4+reg
// global_load_lds: LDS dest = wave-uniform base + lane*16 (verified m104);
// df's fragment-major layout matches exactly.
// fp16 single-pass accuracy verified r4-v17: absmax ~2.8e-17 vs 2.4e-16.

#define D_DIM 128
#define TPG   32   // 16-col tiles per col-group (512 cols); 16 pairs

typedef _Float16 f16x8 __attribute__((ext_vector_type(8)));
typedef _Float16 f16x4 __attribute__((ext_vector_type(4)));
typedef __attribute__((ext_vector_type(4))) float f32x4;

#define C2F   ((float)(0.5 / 2.50662827463100050242 * 1.44269504088896340736))
#define TWOC2 (2.0f * C2F)

// ---- prep: fp32 -> fp16 fragment-major + norms (x: u-term, d: exp'd) ----
__global__ __launch_bounds__(256)
void prep_kernel(const float* __restrict__ x, const float* __restrict__ data,
                 _Float16* __restrict__ xf, _Float16* __restrict__ df,
                 float* __restrict__ xn_u, float* __restrict__ dn_e,
                 float* __restrict__ out, int xThreads, float negLogM) {
    const int gid = blockIdx.x * 256 + threadIdx.x;
    const int which = (gid >= xThreads);
    const int id = which ? (gid - xThreads) : gid;
    const int row = id >> 5, seg = id & 31;
    const float* src = which ? data : x;
    _Float16* dst = which ? df : xf;

    const float4 v = *(const float4*)&src[(size_t)row * D_DIM + seg * 4];

    const int t = row >> 4, r = row & 15;
    const int kc = seg >> 3, q = (seg >> 1) & 3, j0 = (seg & 1) * 4;
    const float sc = which ? 1.0f : TWOC2;   // scale x-side only
    f16x4 h;
    h[0] = (_Float16)(v.x * sc); h[1] = (_Float16)(v.y * sc);
    h[2] = (_Float16)(v.z * sc); h[3] = (_Float16)(v.w * sc);
    *(f16x4*)&dst[((size_t)(t * 4 + kc) * 64 + q * 16 + r) * 8 + j0] = h;

    // norms from UNSCALED values
    float nrm = fmaf(v.x, v.x, fmaf(v.y, v.y, fmaf(v.z, v.z, v.w * v.w)));
#pragma unroll
    for (int off = 1; off < 32; off <<= 1) nrm += __shfl_xor(nrm, off, 64);
    if (seg == 0) {
        if (which) dn_e[row] = __builtin_amdgcn_exp2f(-C2F * nrm);  // pre-exp'd
        else {
            xn_u[row] = fmaf(-C2F, nrm, negLogM);
            out[row]  = 0.0f;                 // fused d_out zeroing
        }
    }
}

// ---- main: 4 waves x 32 rows, LDS-shared B, 2 tiles per barrier ----------
__global__ __launch_bounds__(256)
__attribute__((amdgpu_waves_per_eu(4, 4)))
void kde_f16v18(const _Float16* __restrict__ xf, const _Float16* __restrict__ df,
                const float* __restrict__ xn_u, const float* __restrict__ dn_e,
                float* __restrict__ out, int colGroups) {
    // Double buffer: each holds a PAIR of 16-col B tiles (2 x 4 KB).
    __shared__ _Float16 sh[2][4096];

    const int tid  = threadIdx.x;
    const int lane = tid & 63;
    const int w    = tid >> 6;
    const int q    = lane >> 4;
    const int r    = lane & 15;

    const int bid = blockIdx.x;
    const int cg  = bid % colGroups;
    const int rb  = bid / colGroups;
    const int rowBase  = rb * 128 + w * 32;  // this wave's 32 rows
    const int colTile0 = cg * TPG;

    // A fragments: 8 coalesced dwordx4 loads, once (2 row-tiles).
    f16x8 af0[4], af1[4];
    {
        const int tG0 = rb * 8 + w * 2;
#pragma unroll
        for (int kc = 0; kc < 4; ++kc) {
            af0[kc] = *(const f16x8*)&xf[((size_t)(tG0 * 4 + kc) * 64 + lane) * 8];
            af1[kc] = *(const f16x8*)&xf[((size_t)((tG0 + 1) * 4 + kc) * 64 + lane) * 8];
        }
    }

    // Row terms, consumed as MFMA C-operand init (zero per-tile cost).
    const f32x4 u0 = *(const f32x4*)&xn_u[rowBase + q * 4];
    const f32x4 u1 = *(const f32x4*)&xn_u[rowBase + 16 + q * 4];

    f32x4 srow0 = (f32x4){0.f, 0.f, 0.f, 0.f};
    f32x4 srow1 = (f32x4){0.f, 0.f, 0.f, 0.f};

    const _Float16* dbase = &df[(size_t)colTile0 * 2048];   // 2048 halves/tile
    const float*    nbase = &dn_e[colTile0 * 16 + r];       // pre-exp'd

    // Stage pair p into buffer buf: 8 chunks of 1 KB, 2 per wave.
    auto stagePair = [&](int p, int buf) {
#pragma unroll
        for (int i = 0; i < 2; ++i) {
            const int c  = w * 2 + i;          // 0..7
            const int m  = c >> 2, kc = c & 3;
            const _Float16* g = &dbase[(size_t)(p * 2 + m) * 2048 + (size_t)kc * 512 + (size_t)lane * 8];
            __builtin_amdgcn_global_load_lds(
                (const __attribute__((address_space(1))) void*)g,
                (__attribute__((address_space(3))) void*)&sh[buf][c * 512], 16, 0, 0);
        }
    };

// Compute one 16-col tile (member M of the current pair) from LDS.
// Accumulators start at u0/u1 via the MFMA C input; EDV is the pre-exp'd
// column factor (prefetched plain load, no trans op on the tail).
#define TILE(BUF, M, EDV)                                                         \
    {                                                                             \
        f16x8 b0 = *(const f16x8*)&sh[BUF][((M) * 4 + 0) * 512 + lane * 8];       \
        f16x8 b1 = *(const f16x8*)&sh[BUF][((M) * 4 + 1) * 512 + lane * 8];       \
        f16x8 b2 = *(const f16x8*)&sh[BUF][((M) * 4 + 2) * 512 + lane * 8];       \
        f16x8 b3 = *(const f16x8*)&sh[BUF][((M) * 4 + 3) * 512 + lane * 8];       \
        f32x4 a0 = __builtin_amdgcn_mfma_f32_16x16x32_f16(af0[0], b0, u0, 0, 0, 0); \
        f32x4 a1 = __builtin_amdgcn_mfma_f32_16x16x32_f16(af1[0], b0, u1, 0, 0, 0); \
        a0 = __builtin_amdgcn_mfma_f32_16x16x32_f16(af0[1], b1, a0, 0, 0, 0);     \
        a1 = __builtin_amdgcn_mfma_f32_16x16x32_f16(af1[1], b1, a1, 0, 0, 0);     \
        a0 = __builtin_amdgcn_mfma_f32_16x16x32_f16(af0[2], b2, a0, 0, 0, 0);     \
        a1 = __builtin_amdgcn_mfma_f32_16x16x32_f16(af1[2], b2, a1, 0, 0, 0);     \
        a0 = __builtin_amdgcn_mfma_f32_16x16x32_f16(af0[3], b3, a0, 0, 0, 0);     \
        a1 = __builtin_amdgcn_mfma_f32_16x16x32_f16(af1[3], b3, a1, 0, 0, 0);     \
        srow0[0] = fmaf(__builtin_amdgcn_exp2f(a0[0]), (EDV), srow0[0]);          \
        srow0[1] = fmaf(__builtin_amdgcn_exp2f(a0[1]), (EDV), srow0[1]);          \
        srow0[2] = fmaf(__builtin_amdgcn_exp2f(a0[2]), (EDV), srow0[2]);          \
        srow0[3] = fmaf(__builtin_amdgcn_exp2f(a0[3]), (EDV), srow0[3]);          \
        srow1[0] = fmaf(__builtin_amdgcn_exp2f(a1[0]), (EDV), srow1[0]);          \
        srow1[1] = fmaf(__builtin_amdgcn_exp2f(a1[1]), (EDV), srow1[1]);          \
        srow1[2] = fmaf(__builtin_amdgcn_exp2f(a1[2]), (EDV), srow1[2]);          \
        srow1[3] = fmaf(__builtin_amdgcn_exp2f(a1[3]), (EDV), srow1[3]);          \
    }

    stagePair(0, 0);
    // edv prologue loads (pair 0; thereafter prefetched one pair ahead).
    float e0 = nbase[0];
    float e1 = nbase[16];

#pragma unroll 1
    for (int p = 0; p < TPG / 2; ++p) {
        const int buf = p & 1;
        __syncthreads();                    // drains stage(p) (issued a full
                                            // compute phase ago) + frees buf^1
        float n0 = e0, n1 = e1;
        if (p + 1 < TPG / 2) {
            stagePair(p + 1, buf ^ 1);      // in flight across this compute
            n0 = nbase[(p * 2 + 2) * 16];   // edv prefetch: one pair ahead
            n1 = nbase[(p * 2 + 3) * 16];
        }
        TILE(buf, 0, e0);
        TILE(buf, 1, e1);
        e0 = n0; e1 = n1;
    }

#undef TILE

    // Reduce over the 16 col-lanes (r) and accumulate to out.
#pragma unroll
    for (int p = 0; p < 4; ++p) {
        float s = srow0[p];
        s += __shfl_xor(s, 1, 64);
        s += __shfl_xor(s, 2, 64);
        s += __shfl_xor(s, 4, 64);
        s += __shfl_xor(s, 8, 64);
        if (r == 0) atomicAdd(&out[rowBase + q * 4 + p], s);
        float s1 = srow1[p];
        s1 += __shfl_xor(s1, 1, 64);
        s1 += __shfl_xor(s1, 2, 64);
        s1 += __shfl_xor(s1, 4, 64);
        s1 += __shfl_xor(s1, 8, 64);
        if (r == 0) atomicAdd(&out[rowBase + 16 + q * 4 + p], s1);
    }
}

// ---------------- fallback: round-1 VALU kernel (any size, no ws) ---------
#define BN 128
#define BM 128
#define KT 32
#define LDSS 132

__global__ __launch_bounds__(256, 4)
void kde_valu(const float* __restrict__ x, const float* __restrict__ data,
              float* __restrict__ out, int N, int M) {
    __shared__ float xs[KT][LDSS];
    __shared__ float dsh[KT][LDSS];
    __shared__ float xn_s[BN];
    __shared__ float dn_s[BM];
    const int tid = threadIdx.x;
    const int ty = tid >> 4, tx = tid & 15;
    const int rowBase = blockIdx.y * BN, colBase = blockIdx.x * BM;
    float acc[8][8];
#pragma unroll
    for (int i = 0; i < 8; ++i)
#pragma unroll
        for (int j = 0; j < 8; ++j) acc[i][j] = 0.0f;
    float normAcc = 0.0f;
    for (int kc = 0; kc < D_DIM; kc += KT) {
        __syncthreads();
#pragma unroll
        for (int i = 0; i < 4; ++i) {
            const int idx = tid + i * 256;
            const int row = idx >> 3, kq = idx & 7;
            const float4 v = *(const float4*)&x[(size_t)(rowBase + row) * D_DIM + kc + kq * 4];
            xs[kq * 4 + 0][row] = v.x; xs[kq * 4 + 1][row] = v.y;
            xs[kq * 4 + 2][row] = v.z; xs[kq * 4 + 3][row] = v.w;
            const float4 wv = *(const float4*)&data[(size_t)(colBase + row) * D_DIM + kc + kq * 4];
            dsh[kq * 4 + 0][row] = wv.x; dsh[kq * 4 + 1][row] = wv.y;
            dsh[kq * 4 + 2][row] = wv.z; dsh[kq * 4 + 3][row] = wv.w;
        }
        __syncthreads();
        {
            const float* col = (tid < 128) ? &xs[0][tid] : &dsh[0][tid - 128];
#pragma unroll
            for (int k = 0; k < KT; ++k) { const float v = col[k * LDSS]; normAcc = fmaf(v, v, normAcc); }
        }
#pragma unroll
        for (int k = 0; k < KT; ++k) {
            float a[8], b[8];
            *(float4*)&a[0] = *(const float4*)&xs[k][ty * 8];
            *(float4*)&a[4] = *(const float4*)&xs[k][ty * 8 + 4];
            *(float4*)&b[0] = *(const float4*)&dsh[k][tx * 4];
            *(float4*)&b[4] = *(const float4*)&dsh[k][64 + tx * 4];
#pragma unroll
            for (int i = 0; i < 8; ++i)
#pragma unroll
                for (int j = 0; j < 8; ++j) acc[i][j] = fmaf(a[i], b[j], acc[i][j]);
        }
    }
    if (tid < 128) xn_s[tid] = normAcc; else dn_s[tid - 128] = normAcc;
    __syncthreads();
    const float C2 = C2F;
    const float negLogM = -log2f((float)M);
#pragma unroll
    for (int i = 0; i < 8; ++i) {
        const int row = ty * 8 + i;
        const float xnr = xn_s[row];
        float s = 0.0f;
#pragma unroll
        for (int j = 0; j < 8; ++j) {
            const int col = (j < 4) ? (tx * 4 + j) : (64 + tx * 4 + (j - 4));
            const float sq = xnr + dn_s[col] - 2.0f * acc[i][j];
            s += exp2f(fmaf(-C2, sq, negLogM));
        }
#pragma unroll
        for (int off = 1; off < 16; off <<= 1) s += __shfl_xor(s, off, 64);
        if (tx == 0) atomicAdd(&out[rowBase + row], s);
    }
}

extern "C" void kernel_launch(void* const* d_in, const int* in_sizes, int n_in,
                              void* d_out, int out_size, void* d_ws, size_t ws_size,
                              hipStream_t stream) {
    const float* x    = (const float*)d_in[0];
    const float* data = (const float*)d_in[1];
    float* out = (float*)d_out;
    const int N = in_sizes[0] / D_DIM;
    const int M = in_sizes[1] / D_DIM;

    const size_t need = (size_t)(N + M) * D_DIM * 2 + (size_t)(N + M) * 4;
    if (ws_size < need || (N & 127) || (M & 511)) {
        hipMemsetAsync(d_out, 0, (size_t)out_size * sizeof(float), stream);
        dim3 grid(M / BM, N / BN);
        kde_valu<<<grid, 256, 0, stream>>>(x, data, out, N, M);
        return;
    }

    _Float16* xf = (_Float16*)d_ws;
    _Float16* df = xf + (size_t)N * D_DIM;
    float* xn_u = (float*)(df + (size_t)M * D_DIM);
    float* dn_e = xn_u + N;

    const float negLogM = -log2f((float)M);
    const int xThreads = N * 32;
    const int totThreads = (N + M) * 32;
    prep_kernel<<<totThreads / 256, 256, 0, stream>>>(x, data, xf, df, xn_u, dn_e,
                                                      out, xThreads, negLogM);

    const int colGroups = M / 512;           // 512 cols/group, TPG=32 tiles
    const int rowBlocks = N / 128;
    kde_f16v18<<<rowBlocks * colGroups, 256, 0, stream>>>(xf, df, xn_u, dn_e, out,
                                                          colGroups);
}